// Round 2
// baseline (569435.010 us; speedup 1.0000x reference)
//
#include <hip/hip_runtime.h>
#include <hip/hip_cooperative_groups.h>
#include <hip/hip_bf16.h>
#include <math.h>
#include <stddef.h>

namespace cg = cooperative_groups;

#define B   32
#define TE  400
#define TD  800
#define ED  512
#define DD  80
#define LS  1024
#define G4  4096
#define UN  128
#define FLT 32
#define KW  31
#define NT  512
#define NB  256

// dynamic LDS scratch (floats): max use = phase-1 staging 593*32 = 18976
#define SCR_F 19456

// ws offsets (floats)
#define OFF_H0   0                      // [2][B*LS]
#define OFF_H1   (OFF_H0 + 2*B*LS)      // [2][B*LS]
#define OFF_PQ   (OFF_H1 + 2*B*LS)      // [B*UN]
#define OFF_AL   (OFF_PQ + B*UN)        // [2][B*TE]
#define OFF_DEN  (OFF_AL + 2*B*TE)      // [TD*B]
#define OFF_FLS  (OFF_DEN + TD*B)       // [B*TE*FLT]
#define OFF_KEYS (OFF_FLS + B*TE*FLT)   // [B*TE*UN]
#define ZERO_F   OFF_FLS                // zero [0, OFF_FLS)

__device__ __forceinline__ float fsig(float x){ return 1.f/(1.f+__expf(-x)); }
__device__ __forceinline__ float ftanh(float x){ return 1.f - 2.f/(__expf(2.f*x)+1.f); }

// keys = values @ Wm : [B, TE, UN]
__global__ void keys_kernel(const float* __restrict__ values, const float* __restrict__ Wm,
                            float* __restrict__ keys)
{
    int b  = blockIdx.x;
    int tg = blockIdx.y;      // groups of 8 t_enc rows
    int tid = threadIdx.x;    // 128
    __shared__ __align__(16) float v[8*ED];
    const float* vb = values + (size_t)b*TE*ED + (size_t)tg*8*ED;
    for (int i = tid; i < 8*ED; i += 128) v[i] = vb[i];
    __syncthreads();
    int u = tid;
    float acc[8];
#pragma unroll
    for (int i=0;i<8;i++) acc[i]=0.f;
    for (int k=0;k<ED;k++){
        float w = Wm[k*UN + u];
#pragma unroll
        for (int tt=0; tt<8; tt++) acc[tt] += v[tt*ED + k]*w;
    }
#pragma unroll
    for (int tt=0; tt<8; tt++)
        keys[(size_t)b*TE*UN + (size_t)(tg*8+tt)*UN + u] = acc[tt];
}

// one k-chunk of the 16-col GEMM: thread (b_, kq) accumulates 16 cols over L k's
__device__ __forceinline__ void gemm_chunk(const float* __restrict__ xs, int ckp,
                                           const float* __restrict__ wbase,
                                           int L, int b_, int kq, int u0,
                                           float4 acc[4])
{
    const float* xp = xs + b_*ckp + kq*L;
    const float* wp = wbase + (size_t)(kq*L)*G4 + u0;
    for (int k = 0; k < L; k++){
        float xv = xp[k];
        float4 w0 = *(const float4*)(wp);
        float4 w1 = *(const float4*)(wp + 1024);
        float4 w2 = *(const float4*)(wp + 2048);
        float4 w3 = *(const float4*)(wp + 3072);
        acc[0].x += xv*w0.x; acc[0].y += xv*w0.y; acc[0].z += xv*w0.z; acc[0].w += xv*w0.w;
        acc[1].x += xv*w1.x; acc[1].y += xv*w1.y; acc[1].z += xv*w1.z; acc[1].w += xv*w1.w;
        acc[2].x += xv*w2.x; acc[2].y += xv*w2.y; acc[2].z += xv*w2.z; acc[2].w += xv*w2.w;
        acc[3].x += xv*w3.x; acc[3].y += xv*w3.y; acc[3].z += xv*w3.z; acc[3].w += xv*w3.w;
        wp += G4;
    }
}

__launch_bounds__(NT, 1)
__global__ void persist(const float* __restrict__ enc, const float* __restrict__ dec,
                        const float* __restrict__ Wq,
                        const float* __restrict__ convk, const float* __restrict__ convb,
                        const float* __restrict__ Wloc,
                        const float* __restrict__ v_a, const float* __restrict__ b_a,
                        const float* __restrict__ W0, const float* __restrict__ U0,
                        const float* __restrict__ b0,
                        const float* __restrict__ W1, const float* __restrict__ U1,
                        const float* __restrict__ b1,
                        float* __restrict__ c_out, float* __restrict__ e_out,
                        float* __restrict__ ws)
{
    cg::grid_group grid = cg::this_grid();
    extern __shared__ float sc[];
    __shared__ float wlocs[FLT*UN];   // 16 KB, staged once
    __shared__ float cks[KW*FLT];
    __shared__ float ckb[FLT];
    __shared__ float vas[UN];
    __shared__ float c0s[128];        // cell state layer0: [un*32+b]
    __shared__ float c1s[128];
    __shared__ float invdp[B];

    const int r   = blockIdx.x;
    const int tid = threadIdx.x;

    float* h0buf  = ws + OFF_H0;
    float* h1buf  = ws + OFF_H1;
    float* pqbuf  = ws + OFF_PQ;
    float* albuf  = ws + OFF_AL;
    float* denoms = ws + OFF_DEN;
    float* flsbuf = ws + OFF_FLS;
    float* keys   = ws + OFF_KEYS;

    for (int i = tid; i < FLT*UN; i += NT) wlocs[i] = Wloc[i];
    for (int i = tid; i < KW*FLT; i += NT) cks[i] = convk[i];
    if (tid < FLT) ckb[tid] = convb[tid];
    if (tid < UN)  vas[tid] = v_a[tid];
    if (tid < 128){ c0s[tid] = 0.f; c1s[tid] = 0.f; }
    __syncthreads();

    const int u0 = r*4;          // 4 owned units (both layers)
    const int b_ = tid & 31;
    const int kq = tid >> 5;     // 0..15
    const int sbb = tid >> 4;    // staging: batch row
    const int sl  = tid & 15;    // staging: lane within row

    for (int t = 0; t < TD; t++){
        float* h0new = h0buf + (t&1)*(B*LS);
        const float* h0old = h0buf + ((t&1)^1)*(B*LS);
        float* h1new = h1buf + (t&1)*(B*LS);
        const float* h1old = h1buf + ((t&1)^1)*(B*LS);

        if (tid < B) invdp[tid] = (t==0) ? 0.f : 1.f/denoms[(t-1)*B + tid];
        __syncthreads();

        // ================= PHASE 1: LSTM layer 0 =================
        {
            float4 acc[4];
#pragma unroll
            for (int g=0; g<4; g++){ acc[g].x=0.f; acc[g].y=0.f; acc[g].z=0.f; acc[g].w=0.f; }

            // chunk 0: k 0..591 (dec + context), weights W0
            for (int kk = sl; kk < 592; kk += 16){
                float v;
                if (kk < DD) v = dec[((size_t)sbb*TD + t)*DD + kk];
                else         v = (t==0) ? 0.f
                                 : c_out[((size_t)sbb*TD + (t-1))*ED + (kk-DD)] * invdp[sbb];
                sc[sbb*593 + kk] = v;
            }
            __syncthreads();
            gemm_chunk(sc, 593, W0, 37, b_, kq, u0, acc);
            __syncthreads();
            // chunk 1: h0_old[0..511], weights U0 rows 0..511
            for (int kk = sl; kk < 512; kk += 16) sc[sbb*513 + kk] = h0old[sbb*LS + kk];
            __syncthreads();
            gemm_chunk(sc, 513, U0, 32, b_, kq, u0, acc);
            __syncthreads();
            // chunk 2: h0_old[512..1023], weights U0 rows 512..1023
            for (int kk = sl; kk < 512; kk += 16) sc[sbb*513 + kk] = h0old[sbb*LS + 512 + kk];
            __syncthreads();
            gemm_chunk(sc, 513, U0 + (size_t)512*G4, 32, b_, kq, u0, acc);
            __syncthreads();
            // reduce 16 k-slices
#pragma unroll
            for (int g=0; g<4; g++){
                sc[kq*544 + b_*17 + g*4 + 0] = acc[g].x;
                sc[kq*544 + b_*17 + g*4 + 1] = acc[g].y;
                sc[kq*544 + b_*17 + g*4 + 2] = acc[g].z;
                sc[kq*544 + b_*17 + g*4 + 3] = acc[g].w;
            }
            __syncthreads();
            if (tid < 128){
                int bb = tid & 31, un = tid >> 5;
                float zs[4];
#pragma unroll
                for (int g=0; g<4; g++){
                    float s = b0[g*LS + u0 + un];
#pragma unroll
                    for (int q=0; q<16; q++) s += sc[q*544 + bb*17 + g*4 + un];
                    zs[g] = s;
                }
                float cp = c0s[un*32 + bb];
                float cn = fsig(zs[1])*cp + fsig(zs[0])*ftanh(zs[2]);
                float hn = fsig(zs[3])*ftanh(cn);
                c0s[un*32 + bb] = cn;
                h0new[bb*LS + u0 + un] = hn;
            }
        }
        grid.sync();

        // ================= PHASE 2: LSTM layer 1 =================
        {
            float4 acc[4];
#pragma unroll
            for (int g=0; g<4; g++){ acc[g].x=0.f; acc[g].y=0.f; acc[g].z=0.f; acc[g].w=0.f; }

            for (int c = 0; c < 4; c++){
                const float* src = (c < 2) ? (h0new + sbb*LS + c*512)
                                           : (h1old + sbb*LS + (c-2)*512);
                for (int kk = sl; kk < 512; kk += 16) sc[sbb*513 + kk] = src[kk];
                __syncthreads();
                const float* wb = (c < 2) ? (W1 + (size_t)(c*512)*G4)
                                          : (U1 + (size_t)((c-2)*512)*G4);
                gemm_chunk(sc, 513, wb, 32, b_, kq, u0, acc);
                __syncthreads();
            }
#pragma unroll
            for (int g=0; g<4; g++){
                sc[kq*544 + b_*17 + g*4 + 0] = acc[g].x;
                sc[kq*544 + b_*17 + g*4 + 1] = acc[g].y;
                sc[kq*544 + b_*17 + g*4 + 2] = acc[g].z;
                sc[kq*544 + b_*17 + g*4 + 3] = acc[g].w;
            }
            __syncthreads();
            if (tid < 128){
                int bb = tid & 31, un = tid >> 5;
                float zs[4];
#pragma unroll
                for (int g=0; g<4; g++){
                    float s = b1[g*LS + u0 + un];
#pragma unroll
                    for (int q=0; q<16; q++) s += sc[q*544 + bb*17 + g*4 + un];
                    zs[g] = s;
                }
                float cp = c1s[un*32 + bb];
                float cn = fsig(zs[1])*cp + fsig(zs[0])*ftanh(zs[2]);
                float hn = fsig(zs[3])*ftanh(cn);
                c1s[un*32 + bb] = cn;
                h1new[bb*LS + u0 + un] = hn;
            }
        }
        grid.sync();

        // ============ PHASE 3: pq (blocks 0..63) + conv/align (64..255) ============
        if (r < 64){
            int bg = r >> 3, uq = r & 7;           // 4 batches, 16 units each
            int u = tid & 15, ks = (tid >> 4) & 7, b2 = tid >> 7;
            int bb = bg*4 + b2;
            const float* hp  = h1new + bb*LS + ks*128;
            const float* wqp = Wq + (size_t)(ks*128)*UN + uq*16 + u;
            float a = 0.f;
            for (int k = 0; k < 128; k++) a += hp[k] * wqp[(size_t)k*UN];
            sc[(b2*16 + u)*9 + ks] = a;
            __syncthreads();
            if (tid < 64){
                int b2b = tid >> 4, uu = tid & 15;
                float s = b_a[uq*16 + uu];
#pragma unroll
                for (int k2=0; k2<8; k2++) s += sc[(b2b*16 + uu)*9 + k2];
                pqbuf[(bg*4 + b2b)*UN + uq*16 + uu] = s;
            }
        } else {
            int q = r - 64; int bb = q / 6; int seg = q - bb*6;
            int p0 = seg*67; int len = TE - p0; if (len > 67) len = 67;
            float invd = invdp[bb];
            const float* alsrc = albuf + ((t&1)^1)*(B*TE) + bb*TE;
            float* aldst       = albuf + (t&1)*(B*TE) + bb*TE;
            const float* erow  = e_out + ((size_t)bb*TD + (t>0?t-1:0))*TE;
            float* aw = sc;
            int wstart = p0 - 15, wlen = len + 30;
            if (tid < wlen){
                int p = wstart + tid;
                float v = 0.f;
                if (p >= 0 && p < TE){
                    v = alsrc[p] + ((t==0) ? 0.f : erow[p]*invd);
                    if (p >= p0 && p < p0 + len) aldst[p] = v;
                }
                aw[tid] = v;
            }
            __syncthreads();
            for (int o = tid; o < len*FLT; o += NT){
                int pos = o >> 5, f = o & 31;
                float s = ckb[f];
#pragma unroll
                for (int j=0; j<KW; j++) s += aw[pos + j]*cks[j*FLT + f];
                flsbuf[((size_t)bb*TE + p0 + pos)*FLT + f] = s;
            }
        }
        grid.sync();

        // ============ PHASE 4: energy + denom + context partial ============
        {
            int chunk = r & 7, bb = r >> 3;
            int t0c = chunk*50;
            float* pqL  = sc;            // 128
            float* flsL = sc + 128;      // 1600
            float* elds = sc + 1728;     // 50*129
            float* esum = sc + 8178;     // 50
            if (tid < UN) pqL[tid] = pqbuf[bb*UN + tid];
            for (int i = tid; i < 50*FLT; i += NT)
                flsL[i] = flsbuf[((size_t)bb*TE + t0c)*FLT + i];
            __syncthreads();
            const float* kb = keys + ((size_t)bb*TE + t0c)*UN;
            for (int o = tid; o < 50*UN; o += NT){
                int pos = o >> 7, u = o & 127;
                float loc = 0.f;
                const float* fr = flsL + pos*FLT;
#pragma unroll
                for (int f=0; f<FLT; f++) loc += fr[f]*wlocs[f*UN + u];
                float x = kb[pos*UN + u] + pqL[u] + loc;
                elds[pos*129 + u] = vas[u]*ftanh(x);
            }
            __syncthreads();
            if (tid < 50){
                float e = 0.f;
                for (int uu=0; uu<UN; uu++) e += elds[tid*129 + uu];
                float ex = __expf(e);          // |e| <= sum|v_a| ~ 5: max-free softmax
                e_out[((size_t)bb*TD + t)*TE + t0c + tid] = ex;
                esum[tid] = ex;
            }
            __syncthreads();
            if (tid == 0){
                float s = 0.f;
                for (int p=0; p<50; p++) s += esum[p];
                atomicAdd(&denoms[t*B + bb], s);
            }
            {   // context partial: thread = output dim d
                float a = 0.f;
                const float* vb = enc + ((size_t)bb*TE + t0c)*ED + tid;
                for (int p=0; p<50; p++) a += esum[p]*vb[(size_t)p*ED];
                atomicAdd(&c_out[((size_t)bb*TD + t)*ED + tid], a);
            }
        }
        grid.sync();
    }
}

// normalize e_out and c_out by 1/denom
__global__ void epilogue(const float* __restrict__ denoms,
                         float* __restrict__ c_out, float* __restrict__ e_out)
{
    int blk = blockIdx.x;              // 0..B*TD-1
    int bb = blk / TD, tt = blk - bb*TD;
    float invd = 1.f / denoms[tt*B + bb];
    float* cr = c_out + ((size_t)bb*TD + tt)*ED;
    float* er = e_out + ((size_t)bb*TD + tt)*TE;
    for (int d = threadIdx.x; d < ED; d += 256) cr[d] *= invd;
    for (int p = threadIdx.x; p < TE; p += 256) er[p] *= invd;
}

extern "C" void kernel_launch(void* const* d_in, const int* in_sizes, int n_in,
                              void* d_out, int out_size, void* d_ws, size_t ws_size,
                              hipStream_t stream)
{
    const float* enc   = (const float*)d_in[0];
    const float* dec   = (const float*)d_in[1];
    const float* Wm    = (const float*)d_in[2];
    const float* Wq    = (const float*)d_in[3];
    const float* convk = (const float*)d_in[4];
    const float* convb = (const float*)d_in[5];
    const float* Wloc  = (const float*)d_in[6];
    const float* v_a   = (const float*)d_in[7];
    const float* b_a   = (const float*)d_in[8];
    const float* W0    = (const float*)d_in[9];
    const float* U0    = (const float*)d_in[10];
    const float* b0    = (const float*)d_in[11];
    const float* W1    = (const float*)d_in[12];
    const float* U1    = (const float*)d_in[13];
    const float* b1    = (const float*)d_in[14];

    float* out    = (float*)d_out;
    float* c_outp = out;                               // [B, TD, ED]
    float* e_outp = out + (size_t)B*TD*ED;             // [B, TD, TE]
    float* wsp    = (float*)d_ws;

    // zero: h buffers, pq, align, denoms  (+ c_out, accumulated by atomics)
    hipMemsetAsync(wsp, 0, (size_t)ZERO_F*sizeof(float), stream);
    hipMemsetAsync(c_outp, 0, (size_t)B*TD*ED*sizeof(float), stream);

    keys_kernel<<<dim3(B,50), 128, 0, stream>>>(enc, Wm, wsp + OFF_KEYS);

    hipFuncSetAttribute((const void*)persist,
                        hipFuncAttributeMaxDynamicSharedMemorySize, SCR_F*4);
    void* args[] = { (void*)&enc, (void*)&dec, (void*)&Wq, (void*)&convk, (void*)&convb,
                     (void*)&Wloc, (void*)&v_a, (void*)&b_a, (void*)&W0, (void*)&U0,
                     (void*)&b0, (void*)&W1, (void*)&U1, (void*)&b1,
                     (void*)&c_outp, (void*)&e_outp, (void*)&wsp };
    hipLaunchCooperativeKernel((void*)persist, dim3(NB), dim3(NT), args,
                               SCR_F*4, stream);

    epilogue<<<B*TD, 256, 0, stream>>>(wsp + OFF_DEN, c_outp, e_outp);
}